// Round 12
// baseline (489.138 us; speedup 1.0000x reference)
//
#include <hip/hip_runtime.h>
#include <math.h>

#define NTREE 512
#define NNODE 48
#define HD 256
#define LD 64
#define VOC 800
#define TSTEP 94
#define NFWD 47

typedef __attribute__((ext_vector_type(8))) short s8v;   // 8 bf16 (4 VGPRs)
typedef __attribute__((ext_vector_type(4))) float f4v;   // 4 fp32 acc

// fast device transcendentals (v_exp_f32 + v_rcp_f32), GRU-only
__device__ __forceinline__ float sigm_f(float x) {
    return __builtin_amdgcn_rcpf(1.f + __expf(-x));
}
__device__ __forceinline__ float tanh_f(float x) {
    return 1.f - 2.f * __builtin_amdgcn_rcpf(1.f + __expf(2.f * x));
}

__device__ __forceinline__ float bfu(unsigned short u) {
    union { unsigned int i; float f; } c; c.i = ((unsigned int)u) << 16; return c.f;
}
__device__ __forceinline__ unsigned short f2bf(float f) {
    union { float f; unsigned int u; } c; c.f = f;
    return (unsigned short)((c.u + 0x7fffu + ((c.u >> 16) & 1u)) >> 16);
}
__device__ __forceinline__ s8v frag(const unsigned short* p) {
    union { int4 i; s8v v; } u; u.i = *(const int4*)p; return u.v;
}
__device__ __forceinline__ s8v zfrag() {
    union { int4 i; s8v v; } u; u.i = make_int4(0, 0, 0, 0); return u.v;
}
// LDS-only barrier: global ops (hsb stores, gathers) stay in flight.
__device__ __forceinline__ void bar_lgkm() {
    asm volatile("s_waitcnt lgkmcnt(0)\n\ts_barrier" ::: "memory");
}

// ---------------------------------------------------------------------------
// Precompute x-projections for all 800 vocab words (biases folded in).
// ---------------------------------------------------------------------------
#define PV 8
__global__ __launch_bounds__(256) void prep_xproj(
    const float* __restrict__ emb,
    const float* __restrict__ Wz, const float* __restrict__ bz,
    const float* __restrict__ Wh, const float* __restrict__ bh,
    const float* __restrict__ Wr, const float* __restrict__ br,
    float* __restrict__ xzT, float* __restrict__ xhT, float* __restrict__ xrT)
{
    __shared__ float embL[PV][HD];
    const int j = threadIdx.x;
    const int v0 = blockIdx.x * PV;
    for (int r = 0; r < PV; ++r) embL[r][j] = emb[(v0 + r) * HD + j];
    __syncthreads();

    float az[PV], ah[PV], ar[PV];
#pragma unroll
    for (int r = 0; r < PV; ++r) { az[r] = bz[j]; ah[r] = bh[j]; ar[r] = br[j]; }
    for (int i = 0; i < HD; i += 4) {
        float wz0 = Wz[(i + 0) * HD + j], wz1 = Wz[(i + 1) * HD + j];
        float wz2 = Wz[(i + 2) * HD + j], wz3 = Wz[(i + 3) * HD + j];
        float wh0 = Wh[(i + 0) * HD + j], wh1 = Wh[(i + 1) * HD + j];
        float wh2 = Wh[(i + 2) * HD + j], wh3 = Wh[(i + 3) * HD + j];
        float wr0 = Wr[(i + 0) * HD + j], wr1 = Wr[(i + 1) * HD + j];
        float wr2 = Wr[(i + 2) * HD + j], wr3 = Wr[(i + 3) * HD + j];
#pragma unroll
        for (int r = 0; r < PV; ++r) {
            float4 e = *(const float4*)&embL[r][i];
            az[r] += e.x * wz0 + e.y * wz1 + e.z * wz2 + e.w * wz3;
            ah[r] += e.x * wh0 + e.y * wh1 + e.z * wh2 + e.w * wh3;
            ar[r] += e.x * wr0 + e.y * wr1 + e.z * wr2 + e.w * wr3;
        }
    }
#pragma unroll
    for (int r = 0; r < PV; ++r) {
        xzT[(v0 + r) * HD + j] = az[r];
        xhT[(v0 + r) * HD + j] = ah[r];
        xrT[(v0 + r) * HD + j] = ar[r];
    }
}

// ---------------------------------------------------------------------------
// Fused misc prep: blocks [0,4) init acc; [4,772) tcvt3; [772,2084) tcvtQ;
// [2084, 2084+513) cvtE.
// ---------------------------------------------------------------------------
__global__ __launch_bounds__(256) void prep_misc(
    const float* __restrict__ Wz, const float* __restrict__ Wh,
    const float* __restrict__ Ur,
    const float* __restrict__ Ww, const float* __restrict__ Wow,
    const float* __restrict__ Uw,
    const float* __restrict__ emb, const float* __restrict__ tv,
    unsigned short* __restrict__ WzT, unsigned short* __restrict__ WhT,
    unsigned short* __restrict__ UrT,
    unsigned short* __restrict__ W1T, unsigned short* __restrict__ WoT,
    unsigned short* __restrict__ UwT,
    unsigned short* __restrict__ embB, unsigned short* __restrict__ tvB,
    float* __restrict__ acc)
{
    int b = blockIdx.x;
    if (b < 4) {
        acc[b * 256 + threadIdx.x] = 0.f;
    } else if (b < 772) {
        int bb = b - 4;
        const int which = bb >> 8, n = bb & 255, k = threadIdx.x;
        const float* src = (which == 0) ? (Wz + HD * HD) : (which == 1) ? (Wh + HD * HD) : Ur;
        unsigned short* dst = (which == 0) ? WzT : (which == 1) ? WhT : UrT;
        dst[n * HD + k] = f2bf(src[k * HD + n]);
    } else if (b < 2084) {
        int bb = b - 772;
        if (bb < 256) {
            for (int k = threadIdx.x; k < 320; k += 256)
                W1T[bb * 320 + k] = f2bf(Ww[k * 256 + bb]);
        } else if (bb < 1056) {
            int n = bb - 256;
            WoT[n * 256 + threadIdx.x] = f2bf(Wow[threadIdx.x * VOC + n]);
        } else {
            int n = bb - 1056;
            for (int k = threadIdx.x; k < 576; k += 256)
                UwT[n * 576 + k] = f2bf(Uw[k * 256 + n]);
        }
    } else {
        int idx = (b - 2084) * 256 + threadIdx.x;
        if (idx < VOC * HD) embB[idx] = f2bf(emb[idx]);
        else {
            int i2 = idx - VOC * HD;
            if (i2 < NTREE * LD) tvB[i2] = f2bf(tv[i2]);
        }
    }
}

// ---------------------------------------------------------------------------
// GRU v11 = gru10 + split MFMA chains (2x4 instead of 1x8 per accumulator).
// 256 wgs x 512 thr (8 waves), 2 trees/wg. Wz/Wh tiles in regs; Ur in LDS.
// Shuffle-redistributed finalize, 2 lgkm-only barriers/step.
// ---------------------------------------------------------------------------
__global__ __launch_bounds__(512, 2) void gru11(
    const int* __restrict__ wid,
    const float* __restrict__ xzT, const float* __restrict__ xhT,
    const float* __restrict__ xrT,
    const unsigned short* __restrict__ WzT, const unsigned short* __restrict__ WhT,
    const unsigned short* __restrict__ UrT,
    unsigned short* __restrict__ hsb)
{
    __shared__ unsigned short urL[16 * 8 * 64 * 8];   // 128 KB [tile][kt][lane][8]
    __shared__ unsigned short mBL[2][2][HD], armBL[2][2][HD];
    __shared__ int widL[2][NNODE];

    const int tid = threadIdx.x;
    const int wave = tid >> 6, lane = tid & 63;
    const int lq = lane >> 4, ln = lane & 15;
    const int b0 = blockIdx.x * 2;
    const int T0 = 2 * wave, T1 = T0 + 1;
    const int ftree = lane >> 5;
    const int fcol  = wave * 32 + (lane & 31);
    const int srcl  = lane & 15;
    const bool hi16 = (lane & 16) != 0;
    const bool hi32 = (lane & 32) != 0;

    if (tid < 2 * NNODE) widL[tid / NNODE][tid % NNODE] =
        wid[(b0 + tid / NNODE) * NNODE + (tid % NNODE)];

#pragma unroll
    for (int s = 0; s < 16; ++s) {
        *(int4*)&urL[((s * 8 + wave) * 64 + lane) * 8] =
            *(const int4*)&UrT[(s * 16 + ln) * HD + wave * 32 + lq * 8];
    }

    s8v wz0[8], wz1[8], wh0[8], wh1[8];
#pragma unroll
    for (int kt = 0; kt < 8; ++kt) {
        const int ko = kt * 32 + lq * 8;
        wz0[kt] = frag(&WzT[(T0 * 16 + ln) * HD + ko]);
        wz1[kt] = frag(&WzT[(T1 * 16 + ln) * HD + ko]);
        wh0[kt] = frag(&WhT[(T0 * 16 + ln) * HD + ko]);
        wh1[kt] = frag(&WhT[(T1 * 16 + ln) * HD + ko]);
    }
    __syncthreads();   // widL + urL visible

    float cxz, cxh, cxr, chsp = 0.f, me = 0.f;
    float nxz = 0.f, nxh = 0.f, nxr = 0.f, nhsp = 0.f;
    {
        const int ws = widL[ftree][0], wd = widL[ftree][1];
        cxz = xzT[ws * HD + fcol];
        cxh = xhT[ws * HD + fcol];
        cxr = xrT[wd * HD + fcol];
    }

#pragma unroll 2
    for (int t = 0; t < TSTEP; ++t) {
        const int par = t & 1, nxt = par ^ 1;
        const bool fwd = t < NFWD;
        const bool hp = (t != 0) && (t != NFWD);

        // ---- prefetch for t+1 ----
        {
            if (t == NFWD)
                chsp = bfu(hsb[((NFWD - 2) * NTREE + b0 + ftree) * HD + fcol]);
            const int tn = t + 1;
            if (tn < TSTEP) {
                const bool fwdn = tn < NFWD;
                const int un = TSTEP - tn;
                const int srcn = fwdn ? tn : un;
                const int dstn = fwdn ? (tn + 1) : (un - 1);
                const int ws = widL[ftree][srcn], wd = widL[ftree][dstn];
                nxz = xzT[ws * HD + fcol];
                nxh = xhT[ws * HD + fcol];
                nxr = xrT[wd * HD + fcol];
                nhsp = 0.f;
                if (tn > NFWD && dstn > 0)
                    nhsp = bfu(hsb[((dstn - 1) * NTREE + b0 + ftree) * HD + fcol]);
            }
        }

        // ---- phase A MFMA (2x4 chains) + shuffle redistribute ----
        float az = 0.f, ah = 0.f;
        if (hp) {
            f4v cz0a = (f4v){0.f,0.f,0.f,0.f}, cz0b = cz0a, cz1a = cz0a, cz1b = cz0a;
            f4v ch0a = cz0a, ch0b = cz0a, ch1a = cz0a, ch1b = cz0a;
#pragma unroll
            for (int kt = 0; kt < 4; ++kt) {
                const int ko = kt * 32 + lq * 8;
                s8v am = (ln < 2) ? frag(&mBL[par][ln][ko]) : zfrag();
                s8v aa = (ln < 2) ? frag(&armBL[par][ln][ko]) : zfrag();
                cz0a = __builtin_amdgcn_mfma_f32_16x16x32_bf16(am, wz0[kt], cz0a, 0, 0, 0);
                cz1a = __builtin_amdgcn_mfma_f32_16x16x32_bf16(am, wz1[kt], cz1a, 0, 0, 0);
                ch0a = __builtin_amdgcn_mfma_f32_16x16x32_bf16(aa, wh0[kt], ch0a, 0, 0, 0);
                ch1a = __builtin_amdgcn_mfma_f32_16x16x32_bf16(aa, wh1[kt], ch1a, 0, 0, 0);
            }
#pragma unroll
            for (int kt = 4; kt < 8; ++kt) {
                const int ko = kt * 32 + lq * 8;
                s8v am = (ln < 2) ? frag(&mBL[par][ln][ko]) : zfrag();
                s8v aa = (ln < 2) ? frag(&armBL[par][ln][ko]) : zfrag();
                cz0b = __builtin_amdgcn_mfma_f32_16x16x32_bf16(am, wz0[kt], cz0b, 0, 0, 0);
                cz1b = __builtin_amdgcn_mfma_f32_16x16x32_bf16(am, wz1[kt], cz1b, 0, 0, 0);
                ch0b = __builtin_amdgcn_mfma_f32_16x16x32_bf16(aa, wh0[kt], ch0b, 0, 0, 0);
                ch1b = __builtin_amdgcn_mfma_f32_16x16x32_bf16(aa, wh1[kt], ch1b, 0, 0, 0);
            }
            f4v cz0 = cz0a + cz0b, cz1 = cz1a + cz1b;
            f4v ch0 = ch0a + ch0b, ch1 = ch1a + ch1b;
            float a00 = __shfl(cz0[0], srcl), a01 = __shfl(cz0[1], srcl);
            float a10 = __shfl(cz1[0], srcl), a11 = __shfl(cz1[1], srcl);
            az = hi16 ? (hi32 ? a11 : a10) : (hi32 ? a01 : a00);
            float h00 = __shfl(ch0[0], srcl), h01 = __shfl(ch0[1], srcl);
            float h10 = __shfl(ch1[0], srcl), h11 = __shfl(ch1[1], srcl);
            ah = hi16 ? (hi32 ? h11 : h10) : (hi32 ? h01 : h00);
        }

        // ---- finalize A ----
        {
            float azv = cxz, ahv = cxh, sold = 0.f;
            if (hp) { azv += az; ahv += ah; sold = me; }
            float z = sigm_f(azv), mt = tanh_f(ahv);
            me = sold + z * (mt - sold);
            float hv = fwd ? me : (me + chsp);
            hsb[(t * NTREE + b0 + ftree) * HD + fcol] = f2bf(hv);
            mBL[nxt][ftree][fcol] = f2bf(me);
        }
        bar_lgkm();

        // ---- phase B MFMA (2x4 chains) + shuffle ----
        {
            f4v cr0a = (f4v){0.f,0.f,0.f,0.f}, cr0b = cr0a, cr1a = cr0a, cr1b = cr0a;
#pragma unroll
            for (int kt = 0; kt < 4; ++kt) {
                const int ko = kt * 32 + lq * 8;
                s8v a = (ln < 2) ? frag(&mBL[nxt][ln][ko]) : zfrag();
                s8v b0f = frag(&urL[((T0 * 8 + kt) * 64 + lane) * 8]);
                s8v b1f = frag(&urL[((T1 * 8 + kt) * 64 + lane) * 8]);
                cr0a = __builtin_amdgcn_mfma_f32_16x16x32_bf16(a, b0f, cr0a, 0, 0, 0);
                cr1a = __builtin_amdgcn_mfma_f32_16x16x32_bf16(a, b1f, cr1a, 0, 0, 0);
            }
#pragma unroll
            for (int kt = 4; kt < 8; ++kt) {
                const int ko = kt * 32 + lq * 8;
                s8v a = (ln < 2) ? frag(&mBL[nxt][ln][ko]) : zfrag();
                s8v b0f = frag(&urL[((T0 * 8 + kt) * 64 + lane) * 8]);
                s8v b1f = frag(&urL[((T1 * 8 + kt) * 64 + lane) * 8]);
                cr0b = __builtin_amdgcn_mfma_f32_16x16x32_bf16(a, b0f, cr0b, 0, 0, 0);
                cr1b = __builtin_amdgcn_mfma_f32_16x16x32_bf16(a, b1f, cr1b, 0, 0, 0);
            }
            f4v cr0 = cr0a + cr0b, cr1 = cr1a + cr1b;
            float r00 = __shfl(cr0[0], srcl), r01 = __shfl(cr0[1], srcl);
            float r10 = __shfl(cr1[0], srcl), r11 = __shfl(cr1[1], srcl);
            float ar = hi16 ? (hi32 ? r11 : r10) : (hi32 ? r01 : r00);
            float r = sigm_f(cxr + ar);
            armBL[nxt][ftree][fcol] = f2bf(r * me);
            cxz = nxz; cxh = nxh; cxr = nxr; chsp = nhsp;
        }
        bar_lgkm();
    }
}

// ---------------------------------------------------------------------------
// Fused heads v2: blocks [0,768) = Q, [768,2288) = P. A-fragments loaded
// DIRECTLY from global (hsb/embB/tvB match the MFMA A layout) -- no staging
// LDS. Q stage-2 keeps hid A-frags in registers (loaded once from hidL).
// Branchless 1-exp online softmax.
// ---------------------------------------------------------------------------
#define QG 32
#define PG 32
struct QSmem {
    unsigned short hidL[QG][264];
    int tgts[QG];
    float wred[4][QG][4];
};
struct PSmem {
    int widL[PG];
    float wredp[4][PG];
};

__global__ __launch_bounds__(256) void heads(
    const int* __restrict__ wid,
    const unsigned short* __restrict__ tvB,
    const unsigned short* __restrict__ embB,
    const unsigned short* __restrict__ hsb,
    const unsigned short* __restrict__ W1T,
    const unsigned short* __restrict__ WoT,
    const unsigned short* __restrict__ UwT,
    const float* __restrict__ Wb, const float* __restrict__ Wob,
    const float* __restrict__ Ub,
    const float* __restrict__ Usw, const float* __restrict__ Usb,
    float* __restrict__ acc)
{
    __shared__ __align__(16) char smem[sizeof(QSmem) > sizeof(PSmem) ? sizeof(QSmem) : sizeof(PSmem)];
    const int tid = threadIdx.x;
    const int wave = tid >> 6, lane = tid & 63;
    const int lq = lane >> 4, ln = lane & 15;

    if (blockIdx.x < 768) {
        // ================= Q head =================
        QSmem& S = *(QSmem*)smem;
        const int trow = blockIdx.x >> 4;
        const int b0 = (blockIdx.x & 15) * QG;

        if (tid < QG) S.tgts[tid] = wid[(b0 + tid) * NNODE + trow];

        // stage 1: A direct from global
        f4v acc1[2][4];
#pragma unroll
        for (int mt = 0; mt < 2; ++mt)
#pragma unroll
            for (int nt = 0; nt < 4; ++nt) acc1[mt][nt] = (f4v){0.f, 0.f, 0.f, 0.f};
        const unsigned short* hrow = hsb + (size_t)(trow - 1) * NTREE * HD;
#pragma unroll
        for (int kt = 0; kt < 10; ++kt) {
            s8v a0, a1;
            if (kt < 8) {
                if (trow == 0) { a0 = zfrag(); a1 = zfrag(); }
                else {
                    a0 = frag(&hrow[(b0 + ln) * HD + kt * 32 + lq * 8]);
                    a1 = frag(&hrow[(b0 + 16 + ln) * HD + kt * 32 + lq * 8]);
                }
            } else {
                a0 = frag(&tvB[(b0 + ln) * LD + (kt - 8) * 32 + lq * 8]);
                a1 = frag(&tvB[(b0 + 16 + ln) * LD + (kt - 8) * 32 + lq * 8]);
            }
#pragma unroll
            for (int nt = 0; nt < 4; ++nt) {
                int n = wave * 64 + nt * 16 + ln;
                s8v b = frag(&W1T[n * 320 + kt * 32 + lq * 8]);
                acc1[0][nt] = __builtin_amdgcn_mfma_f32_16x16x32_bf16(a0, b, acc1[0][nt], 0, 0, 0);
                acc1[1][nt] = __builtin_amdgcn_mfma_f32_16x16x32_bf16(a1, b, acc1[1][nt], 0, 0, 0);
            }
        }
#pragma unroll
        for (int nt = 0; nt < 4; ++nt) {
            int col = wave * 64 + nt * 16 + ln;
            float wb = Wb[col];
#pragma unroll
            for (int mt = 0; mt < 2; ++mt)
#pragma unroll
                for (int r = 0; r < 4; ++r)
                    S.hidL[mt * 16 + lq * 4 + r][col] = f2bf(fmaxf(acc1[mt][nt][r] + wb, 0.f));
        }
        __syncthreads();

        // stage 2: hid A-frags -> registers, reused over 13 n-tiles
        s8v ha0[8], ha1[8];
#pragma unroll
        for (int kt = 0; kt < 8; ++kt) {
            ha0[kt] = frag(&S.hidL[ln][kt * 32 + lq * 8]);
            ha1[kt] = frag(&S.hidL[16 + ln][kt * 32 + lq * 8]);
        }

        int rt[2][4];
#pragma unroll
        for (int mt = 0; mt < 2; ++mt)
#pragma unroll
            for (int r = 0; r < 4; ++r) rt[mt][r] = S.tgts[mt * 16 + lq * 4 + r];
        float mx[2][4], ls[2][4], tg[2][4]; int am[2][4];
#pragma unroll
        for (int mt = 0; mt < 2; ++mt)
#pragma unroll
            for (int r = 0; r < 4; ++r) { mx[mt][r] = -1e30f; ls[mt][r] = 0.f; tg[mt][r] = 0.f; am[mt][r] = 1 << 30; }

        for (int nt = wave; nt < 50; nt += 4) {
            int n = nt * 16 + ln;
            const unsigned short* wrow = WoT + n * 256;
            f4v a2[2];
            a2[0] = (f4v){0.f, 0.f, 0.f, 0.f}; a2[1] = (f4v){0.f, 0.f, 0.f, 0.f};
#pragma unroll
            for (int kt = 0; kt < 8; ++kt) {
                s8v b = frag(&wrow[kt * 32 + lq * 8]);
                a2[0] = __builtin_amdgcn_mfma_f32_16x16x32_bf16(ha0[kt], b, a2[0], 0, 0, 0);
                a2[1] = __builtin_amdgcn_mfma_f32_16x16x32_bf16(ha1[kt], b, a2[1], 0, 0, 0);
            }
            float bias = Wob[n];
#pragma unroll
            for (int mt = 0; mt < 2; ++mt)
#pragma unroll
                for (int r = 0; r < 4; ++r) {
                    float v = a2[mt][r] + bias;
                    if (n == rt[mt][r]) tg[mt][r] = v;
                    float d = v - mx[mt][r];
                    float e = __expf(-fabsf(d));
                    bool newmax = d > 0.f;
                    ls[mt][r] = fmaf(ls[mt][r], newmax ? e : 1.f, newmax ? 1.f : e);
                    if (newmax) { mx[mt][r] = v; am[mt][r] = n; }
                }
        }

#pragma unroll
        for (int s = 1; s < 16; s <<= 1) {
#pragma unroll
            for (int mt = 0; mt < 2; ++mt)
#pragma unroll
                for (int r = 0; r < 4; ++r) {
                    float mo = __shfl_xor(mx[mt][r], s);
                    float lo = __shfl_xor(ls[mt][r], s);
                    int   ao = __shfl_xor(am[mt][r], s);
                    float to = __shfl_xor(tg[mt][r], s);
                    tg[mt][r] += to;
                    float nm = fmaxf(mx[mt][r], mo);
                    ls[mt][r] = ls[mt][r] * __expf(mx[mt][r] - nm) + lo * __expf(mo - nm);
                    if (mo > mx[mt][r] || (mo == mx[mt][r] && ao < am[mt][r])) am[mt][r] = ao;
                    mx[mt][r] = nm;
                }
        }
        if (ln == 0) {
#pragma unroll
            for (int mt = 0; mt < 2; ++mt)
#pragma unroll
                for (int r = 0; r < 4; ++r) {
                    int row = mt * 16 + lq * 4 + r;
                    S.wred[wave][row][0] = mx[mt][r];
                    S.wred[wave][row][1] = ls[mt][r];
                    S.wred[wave][row][2] = __int_as_float(am[mt][r]);
                    S.wred[wave][row][3] = tg[mt][r];
                }
        }
        __syncthreads();

        float lossv = 0.f, corrv = 0.f;
        if (tid < QG) {
            float m_ = -1e30f, l_ = 0.f, t_ = 0.f; int a_ = 1 << 30;
#pragma unroll
            for (int w = 0; w < 4; ++w) {
                float mo = S.wred[w][tid][0], lo = S.wred[w][tid][1], to = S.wred[w][tid][3];
                int ao = __float_as_int(S.wred[w][tid][2]);
                t_ += to;
                float nm = fmaxf(m_, mo);
                l_ = l_ * __expf(m_ - nm) + lo * __expf(mo - nm);
                if (mo > m_ || (mo == m_ && ao < a_)) a_ = ao;
                m_ = nm;
            }
            lossv = m_ + logf(l_) - t_;
            corrv = (a_ == S.tgts[tid]) ? 1.f : 0.f;
        }
        if (wave == 0) {
            for (int s = 32; s; s >>= 1) {
                lossv += __shfl_down(lossv, s);
                corrv += __shfl_down(corrv, s);
            }
            if (tid == 0) {
                int slot = blockIdx.x & 255;
                atomicAdd(&acc[0 * 256 + slot], lossv);
                atomicAdd(&acc[2 * 256 + slot], corrv);
            }
        }
    } else {
        // ================= P head =================
        PSmem& S = *(PSmem*)smem;
        const int pb = blockIdx.x - 768;
        const int trow = pb >> 4;
        const int b0 = (pb & 15) * PG;
        const int node = (trow == 0) ? 0 : ((trow <= NFWD) ? trow : (TSTEP - trow));

        if (tid < PG) S.widL[tid] = wid[(b0 + tid) * NNODE + node];
        __syncthreads();
        const int w0 = S.widL[ln], w1 = S.widL[16 + ln];
        const unsigned short* hrow = hsb + (size_t)(trow - 1) * NTREE * HD;

        f4v a1[2][4];
#pragma unroll
        for (int mt = 0; mt < 2; ++mt)
#pragma unroll
            for (int nt = 0; nt < 4; ++nt) a1[mt][nt] = (f4v){0.f, 0.f, 0.f, 0.f};
#pragma unroll 2
        for (int kt = 0; kt < 18; ++kt) {
            s8v a0, am_;
            if (kt < 8) {
                a0  = frag(&embB[w0 * HD + kt * 32 + lq * 8]);
                am_ = frag(&embB[w1 * HD + kt * 32 + lq * 8]);
            } else if (kt < 16) {
                if (trow == 0) { a0 = zfrag(); am_ = zfrag(); }
                else {
                    a0  = frag(&hrow[(b0 + ln) * HD + (kt - 8) * 32 + lq * 8]);
                    am_ = frag(&hrow[(b0 + 16 + ln) * HD + (kt - 8) * 32 + lq * 8]);
                }
            } else {
                a0  = frag(&tvB[(b0 + ln) * LD + (kt - 16) * 32 + lq * 8]);
                am_ = frag(&tvB[(b0 + 16 + ln) * LD + (kt - 16) * 32 + lq * 8]);
            }
#pragma unroll
            for (int nt = 0; nt < 4; ++nt) {
                int n = wave * 64 + nt * 16 + ln;
                s8v b = frag(&UwT[n * 576 + kt * 32 + lq * 8]);
                a1[0][nt] = __builtin_amdgcn_mfma_f32_16x16x32_bf16(a0, b, a1[0][nt], 0, 0, 0);
                a1[1][nt] = __builtin_amdgcn_mfma_f32_16x16x32_bf16(am_, b, a1[1][nt], 0, 0, 0);
            }
        }
        float part[2][4] = {{0, 0, 0, 0}, {0, 0, 0, 0}};
#pragma unroll
        for (int nt = 0; nt < 4; ++nt) {
            int n = wave * 64 + nt * 16 + ln;
            float ub = Ub[n], us = Usw[n];
#pragma unroll
            for (int mt = 0; mt < 2; ++mt)
#pragma unroll
                for (int r = 0; r < 4; ++r)
                    part[mt][r] += fmaxf(a1[mt][nt][r] + ub, 0.f) * us;
        }
#pragma unroll
        for (int s = 1; s < 16; s <<= 1) {
#pragma unroll
            for (int mt = 0; mt < 2; ++mt)
#pragma unroll
                for (int r = 0; r < 4; ++r)
                    part[mt][r] += __shfl_xor(part[mt][r], s);
        }
        if (ln == 0) {
#pragma unroll
            for (int mt = 0; mt < 2; ++mt)
#pragma unroll
                for (int r = 0; r < 4; ++r)
                    S.wredp[wave][mt * 16 + lq * 4 + r] = part[mt][r];
        }
        __syncthreads();

        float lossv = 0.f, corrv = 0.f;
        if (tid < PG) {
            float p = S.wredp[0][tid] + S.wredp[1][tid] + S.wredp[2][tid] + S.wredp[3][tid] + Usb[0];
            float tgt = (trow < NFWD) ? 1.f : 0.f;
            lossv = fmaxf(p, 0.f) - p * tgt + log1pf(expf(-fabsf(p)));
            corrv = (((p > 0.f) ? 1 : 0) == ((trow < NFWD) ? 1 : 0)) ? 1.f : 0.f;
        }
        if (wave == 0) {
            for (int s = 32; s; s >>= 1) {
                lossv += __shfl_down(lossv, s);
                corrv += __shfl_down(corrv, s);
            }
            if (tid == 0) {
                int slot = blockIdx.x & 255;
                atomicAdd(&acc[1 * 256 + slot], lossv);
                atomicAdd(&acc[3 * 256 + slot], corrv);
            }
        }
    }
}

__global__ void fin_kernel(const float* __restrict__ acc, float* __restrict__ out) {
    const int tid = threadIdx.x;
    const int c = tid >> 6, lane = tid & 63;
    float v = 0.f;
    for (int i = lane; i < 256; i += 64) v += acc[c * 256 + i];
    for (int s = 32; s; s >>= 1) v += __shfl_down(v, s);
    if (lane == 0) {
        const float sc[4] = {1.f / 512.f, 1.f / 512.f, 1.f / 24576.f, 1.f / 48640.f};
        out[c] = v * sc[c];
    }
}

extern "C" void kernel_launch(void* const* d_in, const int* in_sizes, int n_in,
                              void* d_out, int out_size, void* d_ws, size_t ws_size,
                              hipStream_t stream) {
    const int*   wid  = (const int*)  d_in[12];
    const float* tv   = (const float*)d_in[13];
    const float* emb  = (const float*)d_in[14];
    const float* Wz   = (const float*)d_in[15];
    const float* bz   = (const float*)d_in[16];
    const float* Wr   = (const float*)d_in[17];
    const float* Ur   = (const float*)d_in[18];
    const float* br   = (const float*)d_in[19];
    const float* Wh   = (const float*)d_in[20];
    const float* bh   = (const float*)d_in[21];
    const float* Ww   = (const float*)d_in[22];
    const float* Wb   = (const float*)d_in[23];
    const float* Uw   = (const float*)d_in[24];
    const float* Ubias= (const float*)d_in[25];
    const float* Wow  = (const float*)d_in[26];
    const float* Wob  = (const float*)d_in[27];
    const float* Usw  = (const float*)d_in[28];
    const float* Usb  = (const float*)d_in[29];

    char* w = (char*)d_ws;
    float* accb = (float*)w;                                 // 4 KB
    float* xzT  = (float*)(w + 4096);                        // 800*256 f32
    float* xhT  = (float*)(w + 823296);
    float* xrT  = (float*)(w + 1642496);
    unsigned short* WzT2 = (unsigned short*)(w + 2461696);   // [256 n][256 k] bf16
    unsigned short* WhT2 = (unsigned short*)(w + 2592768);
    unsigned short* UrT2 = (unsigned short*)(w + 2723840);
    unsigned short* hsb  = (unsigned short*)(w + 2854912);   // 94*512*256 bf16
    unsigned short* W1T  = (unsigned short*)(w + 27496448);  // [256][320]
    unsigned short* WoT  = (unsigned short*)(w + 27660288);  // [800][256]
    unsigned short* UwT  = (unsigned short*)(w + 28069888);  // [256][576]
    unsigned short* embB = (unsigned short*)(w + 28364800);  // [800][256]
    unsigned short* tvB  = (unsigned short*)(w + 28774400);  // [512][64]

    prep_xproj<<<VOC / PV, 256, 0, stream>>>(emb, Wz, bz, Wh, bh, Wr, br, xzT, xhT, xrT);
    prep_misc<<<2084 + 513, 256, 0, stream>>>(Wz, Wh, Ur, Ww, Wow, Uw, emb, tv,
                                              WzT2, WhT2, UrT2, W1T, WoT, UwT,
                                              embB, tvB, accb);
    gru11<<<NTREE / 2, 512, 0, stream>>>(wid, xzT, xhT, xrT, WzT2, WhT2, UrT2, hsb);
    heads<<<768 + 1520, 256, 0, stream>>>(wid, tvB, embB, hsb, W1T, WoT, UwT,
                                          Wb, Wob, Ubias, Usw, Usb, accb);
    fin_kernel<<<1, 256, 0, stream>>>(accb, (float*)d_out);
}

// Round 14
// 447.613 us; speedup vs baseline: 1.0928x; 1.0928x over previous
//
#include <hip/hip_runtime.h>
#include <math.h>

#define NTREE 512
#define NNODE 48
#define HD 256
#define LD 64
#define VOC 800
#define TSTEP 94
#define NFWD 47

typedef __attribute__((ext_vector_type(8))) short s8v;   // 8 bf16 (4 VGPRs)
typedef __attribute__((ext_vector_type(4))) float f4v;   // 4 fp32 acc

// fast device transcendentals (v_exp_f32 + v_rcp_f32), GRU-only
__device__ __forceinline__ float sigm_f(float x) {
    return __builtin_amdgcn_rcpf(1.f + __expf(-x));
}
__device__ __forceinline__ float tanh_f(float x) {
    return 1.f - 2.f * __builtin_amdgcn_rcpf(1.f + __expf(2.f * x));
}

__device__ __forceinline__ float bfu(unsigned short u) {
    union { unsigned int i; float f; } c; c.i = ((unsigned int)u) << 16; return c.f;
}
__device__ __forceinline__ unsigned short f2bf(float f) {
    union { float f; unsigned int u; } c; c.f = f;
    return (unsigned short)((c.u + 0x7fffu + ((c.u >> 16) & 1u)) >> 16);
}
__device__ __forceinline__ s8v frag(const unsigned short* p) {
    union { int4 i; s8v v; } u; u.i = *(const int4*)p; return u.v;
}
__device__ __forceinline__ s8v zfrag() {
    union { int4 i; s8v v; } u; u.i = make_int4(0, 0, 0, 0); return u.v;
}
// LDS-only barrier: global ops (hsb stores, gathers) stay in flight.
__device__ __forceinline__ void bar_lgkm() {
    asm volatile("s_waitcnt lgkmcnt(0)\n\ts_barrier" ::: "memory");
}

// ---------------------------------------------------------------------------
// Precompute x-projections for all 800 vocab words (biases folded in).
// ---------------------------------------------------------------------------
#define PV 8
__global__ __launch_bounds__(256) void prep_xproj(
    const float* __restrict__ emb,
    const float* __restrict__ Wz, const float* __restrict__ bz,
    const float* __restrict__ Wh, const float* __restrict__ bh,
    const float* __restrict__ Wr, const float* __restrict__ br,
    float* __restrict__ xzT, float* __restrict__ xhT, float* __restrict__ xrT)
{
    __shared__ float embL[PV][HD];
    const int j = threadIdx.x;
    const int v0 = blockIdx.x * PV;
    for (int r = 0; r < PV; ++r) embL[r][j] = emb[(v0 + r) * HD + j];
    __syncthreads();

    float az[PV], ah[PV], ar[PV];
#pragma unroll
    for (int r = 0; r < PV; ++r) { az[r] = bz[j]; ah[r] = bh[j]; ar[r] = br[j]; }
    for (int i = 0; i < HD; i += 4) {
        float wz0 = Wz[(i + 0) * HD + j], wz1 = Wz[(i + 1) * HD + j];
        float wz2 = Wz[(i + 2) * HD + j], wz3 = Wz[(i + 3) * HD + j];
        float wh0 = Wh[(i + 0) * HD + j], wh1 = Wh[(i + 1) * HD + j];
        float wh2 = Wh[(i + 2) * HD + j], wh3 = Wh[(i + 3) * HD + j];
        float wr0 = Wr[(i + 0) * HD + j], wr1 = Wr[(i + 1) * HD + j];
        float wr2 = Wr[(i + 2) * HD + j], wr3 = Wr[(i + 3) * HD + j];
#pragma unroll
        for (int r = 0; r < PV; ++r) {
            float4 e = *(const float4*)&embL[r][i];
            az[r] += e.x * wz0 + e.y * wz1 + e.z * wz2 + e.w * wz3;
            ah[r] += e.x * wh0 + e.y * wh1 + e.z * wh2 + e.w * wh3;
            ar[r] += e.x * wr0 + e.y * wr1 + e.z * wr2 + e.w * wr3;
        }
    }
#pragma unroll
    for (int r = 0; r < PV; ++r) {
        xzT[(v0 + r) * HD + j] = az[r];
        xhT[(v0 + r) * HD + j] = ah[r];
        xrT[(v0 + r) * HD + j] = ar[r];
    }
}

// ---------------------------------------------------------------------------
// Fused misc prep: [0,4) init acc; [4,772) tcvt3; [772,2084) tcvtQ;
// [2084, 3012) cvtE  (928 blocks = ceil((800*256 + 512*64)/256) -- exact).
// ---------------------------------------------------------------------------
__global__ __launch_bounds__(256) void prep_misc(
    const float* __restrict__ Wz, const float* __restrict__ Wh,
    const float* __restrict__ Ur,
    const float* __restrict__ Ww, const float* __restrict__ Wow,
    const float* __restrict__ Uw,
    const float* __restrict__ emb, const float* __restrict__ tv,
    unsigned short* __restrict__ WzT, unsigned short* __restrict__ WhT,
    unsigned short* __restrict__ UrT,
    unsigned short* __restrict__ W1T, unsigned short* __restrict__ WoT,
    unsigned short* __restrict__ UwT,
    unsigned short* __restrict__ embB, unsigned short* __restrict__ tvB,
    float* __restrict__ acc)
{
    int b = blockIdx.x;
    if (b < 4) {
        acc[b * 256 + threadIdx.x] = 0.f;
    } else if (b < 772) {
        int bb = b - 4;
        const int which = bb >> 8, n = bb & 255, k = threadIdx.x;
        const float* src = (which == 0) ? (Wz + HD * HD) : (which == 1) ? (Wh + HD * HD) : Ur;
        unsigned short* dst = (which == 0) ? WzT : (which == 1) ? WhT : UrT;
        dst[n * HD + k] = f2bf(src[k * HD + n]);
    } else if (b < 2084) {
        int bb = b - 772;
        if (bb < 256) {
            for (int k = threadIdx.x; k < 320; k += 256)
                W1T[bb * 320 + k] = f2bf(Ww[k * 256 + bb]);
        } else if (bb < 1056) {
            int n = bb - 256;
            WoT[n * 256 + threadIdx.x] = f2bf(Wow[threadIdx.x * VOC + n]);
        } else {
            int n = bb - 1056;
            for (int k = threadIdx.x; k < 576; k += 256)
                UwT[n * 576 + k] = f2bf(Uw[k * 256 + n]);
        }
    } else {
        int idx = (b - 2084) * 256 + threadIdx.x;
        if (idx < VOC * HD) embB[idx] = f2bf(emb[idx]);
        else {
            int i2 = idx - VOC * HD;
            if (i2 < NTREE * LD) tvB[i2] = f2bf(tv[i2]);
        }
    }
}

// ---------------------------------------------------------------------------
// GRU v10 body (champion, 199 us). 256 wgs x 512 thr, 2 trees/wg.
// Wz/Wh tiles in regs; Ur in LDS fragment-contiguous. Shuffle finalize,
// 2 lgkm-only barriers/step.
// ---------------------------------------------------------------------------
__global__ __launch_bounds__(512, 2) void gru10(
    const int* __restrict__ wid,
    const float* __restrict__ xzT, const float* __restrict__ xhT,
    const float* __restrict__ xrT,
    const unsigned short* __restrict__ WzT, const unsigned short* __restrict__ WhT,
    const unsigned short* __restrict__ UrT,
    unsigned short* __restrict__ hsb)
{
    __shared__ unsigned short urL[16 * 8 * 64 * 8];   // 128 KB [tile][kt][lane][8]
    __shared__ unsigned short mBL[2][2][HD], armBL[2][2][HD];
    __shared__ int widL[2][NNODE];

    const int tid = threadIdx.x;
    const int wave = tid >> 6, lane = tid & 63;
    const int lq = lane >> 4, ln = lane & 15;
    const int b0 = blockIdx.x * 2;
    const int T0 = 2 * wave, T1 = T0 + 1;
    const int ftree = lane >> 5;
    const int fcol  = wave * 32 + (lane & 31);
    const int srcl  = lane & 15;
    const bool hi16 = (lane & 16) != 0;
    const bool hi32 = (lane & 32) != 0;

    if (tid < 2 * NNODE) widL[tid / NNODE][tid % NNODE] =
        wid[(b0 + tid / NNODE) * NNODE + (tid % NNODE)];

#pragma unroll
    for (int s = 0; s < 16; ++s) {
        *(int4*)&urL[((s * 8 + wave) * 64 + lane) * 8] =
            *(const int4*)&UrT[(s * 16 + ln) * HD + wave * 32 + lq * 8];
    }

    s8v wz0[8], wz1[8], wh0[8], wh1[8];
#pragma unroll
    for (int kt = 0; kt < 8; ++kt) {
        const int ko = kt * 32 + lq * 8;
        wz0[kt] = frag(&WzT[(T0 * 16 + ln) * HD + ko]);
        wz1[kt] = frag(&WzT[(T1 * 16 + ln) * HD + ko]);
        wh0[kt] = frag(&WhT[(T0 * 16 + ln) * HD + ko]);
        wh1[kt] = frag(&WhT[(T1 * 16 + ln) * HD + ko]);
    }
    __syncthreads();   // widL + urL visible

    float cxz, cxh, cxr, chsp = 0.f, me = 0.f;
    float nxz = 0.f, nxh = 0.f, nxr = 0.f, nhsp = 0.f;
    {
        const int ws = widL[ftree][0], wd = widL[ftree][1];
        cxz = xzT[ws * HD + fcol];
        cxh = xhT[ws * HD + fcol];
        cxr = xrT[wd * HD + fcol];
    }

#pragma unroll 2
    for (int t = 0; t < TSTEP; ++t) {
        const int par = t & 1, nxt = par ^ 1;
        const bool fwd = t < NFWD;
        const bool hp = (t != 0) && (t != NFWD);

        // ---- prefetch for t+1 ----
        {
            if (t == NFWD)
                chsp = bfu(hsb[((NFWD - 2) * NTREE + b0 + ftree) * HD + fcol]);
            const int tn = t + 1;
            if (tn < TSTEP) {
                const bool fwdn = tn < NFWD;
                const int un = TSTEP - tn;
                const int srcn = fwdn ? tn : un;
                const int dstn = fwdn ? (tn + 1) : (un - 1);
                const int ws = widL[ftree][srcn], wd = widL[ftree][dstn];
                nxz = xzT[ws * HD + fcol];
                nxh = xhT[ws * HD + fcol];
                nxr = xrT[wd * HD + fcol];
                nhsp = 0.f;
                if (tn > NFWD && dstn > 0)
                    nhsp = bfu(hsb[((dstn - 1) * NTREE + b0 + ftree) * HD + fcol]);
            }
        }

        // ---- phase A MFMA + shuffle redistribute: az, ah ----
        float az = 0.f, ah = 0.f;
        if (hp) {
            f4v cz0 = (f4v){0.f,0.f,0.f,0.f}, cz1 = cz0, ch0 = cz0, ch1 = cz0;
#pragma unroll
            for (int kt = 0; kt < 8; ++kt) {
                const int ko = kt * 32 + lq * 8;
                s8v am = (ln < 2) ? frag(&mBL[par][ln][ko]) : zfrag();
                s8v aa = (ln < 2) ? frag(&armBL[par][ln][ko]) : zfrag();
                cz0 = __builtin_amdgcn_mfma_f32_16x16x32_bf16(am, wz0[kt], cz0, 0, 0, 0);
                cz1 = __builtin_amdgcn_mfma_f32_16x16x32_bf16(am, wz1[kt], cz1, 0, 0, 0);
                ch0 = __builtin_amdgcn_mfma_f32_16x16x32_bf16(aa, wh0[kt], ch0, 0, 0, 0);
                ch1 = __builtin_amdgcn_mfma_f32_16x16x32_bf16(aa, wh1[kt], ch1, 0, 0, 0);
            }
            float a00 = __shfl(cz0[0], srcl), a01 = __shfl(cz0[1], srcl);
            float a10 = __shfl(cz1[0], srcl), a11 = __shfl(cz1[1], srcl);
            az = hi16 ? (hi32 ? a11 : a10) : (hi32 ? a01 : a00);
            float h00 = __shfl(ch0[0], srcl), h01 = __shfl(ch0[1], srcl);
            float h10 = __shfl(ch1[0], srcl), h11 = __shfl(ch1[1], srcl);
            ah = hi16 ? (hi32 ? h11 : h10) : (hi32 ? h01 : h00);
        }

        // ---- finalize A ----
        {
            float azv = cxz, ahv = cxh, sold = 0.f;
            if (hp) { azv += az; ahv += ah; sold = me; }
            float z = sigm_f(azv), mt = tanh_f(ahv);
            me = sold + z * (mt - sold);
            float hv = fwd ? me : (me + chsp);
            hsb[(t * NTREE + b0 + ftree) * HD + fcol] = f2bf(hv);
            mBL[nxt][ftree][fcol] = f2bf(me);
        }
        bar_lgkm();

        // ---- phase B MFMA + shuffle: ar = m_e @ Ur ----
        {
            f4v cr0 = (f4v){0.f,0.f,0.f,0.f}, cr1 = cr0;
#pragma unroll
            for (int kt = 0; kt < 8; ++kt) {
                const int ko = kt * 32 + lq * 8;
                s8v a = (ln < 2) ? frag(&mBL[nxt][ln][ko]) : zfrag();
                s8v b0f = frag(&urL[((T0 * 8 + kt) * 64 + lane) * 8]);
                s8v b1f = frag(&urL[((T1 * 8 + kt) * 64 + lane) * 8]);
                cr0 = __builtin_amdgcn_mfma_f32_16x16x32_bf16(a, b0f, cr0, 0, 0, 0);
                cr1 = __builtin_amdgcn_mfma_f32_16x16x32_bf16(a, b1f, cr1, 0, 0, 0);
            }
            float r00 = __shfl(cr0[0], srcl), r01 = __shfl(cr0[1], srcl);
            float r10 = __shfl(cr1[0], srcl), r11 = __shfl(cr1[1], srcl);
            float ar = hi16 ? (hi32 ? r11 : r10) : (hi32 ? r01 : r00);
            float r = sigm_f(cxr + ar);
            armBL[nxt][ftree][fcol] = f2bf(r * me);
            cxz = nxz; cxh = nxh; cxr = nxr; chsp = nhsp;
        }
        bar_lgkm();
    }
}

// ---------------------------------------------------------------------------
// Fused heads: [0,768) = Q, [768,2288) = P. Staged LDS inputs (R11-proven);
// branchless 1-exp online softmax; stage-2 ha-frags cached in registers.
// ---------------------------------------------------------------------------
#define QG 32
#define PG 32
struct QSmem {
    unsigned short X1L[QG][328];
    unsigned short hidL[QG][264];
    int tgts[QG];
    float wred[4][QG][4];
};
struct PSmem {
    unsigned short XL[PG][584];
    int widL[PG];
    float wredp[4][PG];
};

__global__ __launch_bounds__(256) void heads(
    const int* __restrict__ wid,
    const unsigned short* __restrict__ tvB,
    const unsigned short* __restrict__ embB,
    const unsigned short* __restrict__ hsb,
    const unsigned short* __restrict__ W1T,
    const unsigned short* __restrict__ WoT,
    const unsigned short* __restrict__ UwT,
    const float* __restrict__ Wb, const float* __restrict__ Wob,
    const float* __restrict__ Ub,
    const float* __restrict__ Usw, const float* __restrict__ Usb,
    float* __restrict__ acc)
{
    __shared__ __align__(16) char smem[sizeof(QSmem) > sizeof(PSmem) ? sizeof(QSmem) : sizeof(PSmem)];
    const int tid = threadIdx.x;
    const int wave = tid >> 6, lane = tid & 63;
    const int lq = lane >> 4, ln = lane & 15;

    if (blockIdx.x < 768) {
        // ================= Q head =================
        QSmem& S = *(QSmem*)smem;
        const int trow = blockIdx.x >> 4;
        const int b0 = (blockIdx.x & 15) * QG;

        if (tid < QG) S.tgts[tid] = wid[(b0 + tid) * NNODE + trow];
        if (trow == 0) {
            int4 z = make_int4(0, 0, 0, 0);
            for (int idx = tid; idx < QG * 32; idx += 256) {
                int m = idx >> 5, c = idx & 31;
                *(int4*)&S.X1L[m][c * 8] = z;
            }
        } else {
            const unsigned short* hrow = hsb + (size_t)(trow - 1) * NTREE * HD;
            for (int idx = tid; idx < QG * 32; idx += 256) {
                int m = idx >> 5, c = idx & 31;
                *(int4*)&S.X1L[m][c * 8] = *(const int4*)&hrow[(b0 + m) * HD + c * 8];
            }
        }
        for (int idx = tid; idx < QG * 8; idx += 256) {
            int m = idx >> 3, c = idx & 7;
            *(int4*)&S.X1L[m][256 + c * 8] = *(const int4*)&tvB[(b0 + m) * LD + c * 8];
        }
        __syncthreads();

        f4v acc1[2][4];
#pragma unroll
        for (int mt = 0; mt < 2; ++mt)
#pragma unroll
            for (int nt = 0; nt < 4; ++nt) acc1[mt][nt] = (f4v){0.f, 0.f, 0.f, 0.f};
#pragma unroll
        for (int kt = 0; kt < 10; ++kt) {
            s8v a0 = frag(&S.X1L[ln][kt * 32 + lq * 8]);
            s8v a1 = frag(&S.X1L[16 + ln][kt * 32 + lq * 8]);
#pragma unroll
            for (int nt = 0; nt < 4; ++nt) {
                int n = wave * 64 + nt * 16 + ln;
                s8v b = frag(&W1T[n * 320 + kt * 32 + lq * 8]);
                acc1[0][nt] = __builtin_amdgcn_mfma_f32_16x16x32_bf16(a0, b, acc1[0][nt], 0, 0, 0);
                acc1[1][nt] = __builtin_amdgcn_mfma_f32_16x16x32_bf16(a1, b, acc1[1][nt], 0, 0, 0);
            }
        }
#pragma unroll
        for (int nt = 0; nt < 4; ++nt) {
            int col = wave * 64 + nt * 16 + ln;
            float wb = Wb[col];
#pragma unroll
            for (int mt = 0; mt < 2; ++mt)
#pragma unroll
                for (int r = 0; r < 4; ++r)
                    S.hidL[mt * 16 + lq * 4 + r][col] = f2bf(fmaxf(acc1[mt][nt][r] + wb, 0.f));
        }
        __syncthreads();

        // stage 2: hid A-frags cached in registers (was 13x LDS re-read)
        s8v ha0[8], ha1[8];
#pragma unroll
        for (int kt = 0; kt < 8; ++kt) {
            ha0[kt] = frag(&S.hidL[ln][kt * 32 + lq * 8]);
            ha1[kt] = frag(&S.hidL[16 + ln][kt * 32 + lq * 8]);
        }

        int rt[2][4];
#pragma unroll
        for (int mt = 0; mt < 2; ++mt)
#pragma unroll
            for (int r = 0; r < 4; ++r) rt[mt][r] = S.tgts[mt * 16 + lq * 4 + r];
        float mx[2][4], ls[2][4], tg[2][4]; int am[2][4];
#pragma unroll
        for (int mt = 0; mt < 2; ++mt)
#pragma unroll
            for (int r = 0; r < 4; ++r) { mx[mt][r] = -1e30f; ls[mt][r] = 0.f; tg[mt][r] = 0.f; am[mt][r] = 1 << 30; }

        for (int nt = wave; nt < 50; nt += 4) {
            int n = nt * 16 + ln;
            const unsigned short* wrow = WoT + n * 256;
            f4v a2[2];
            a2[0] = (f4v){0.f, 0.f, 0.f, 0.f}; a2[1] = (f4v){0.f, 0.f, 0.f, 0.f};
#pragma unroll
            for (int kt = 0; kt < 8; ++kt) {
                s8v b = frag(&wrow[kt * 32 + lq * 8]);
                a2[0] = __builtin_amdgcn_mfma_f32_16x16x32_bf16(ha0[kt], b, a2[0], 0, 0, 0);
                a2[1] = __builtin_amdgcn_mfma_f32_16x16x32_bf16(ha1[kt], b, a2[1], 0, 0, 0);
            }
            float bias = Wob[n];
#pragma unroll
            for (int mt = 0; mt < 2; ++mt)
#pragma unroll
                for (int r = 0; r < 4; ++r) {
                    float v = a2[mt][r] + bias;
                    if (n == rt[mt][r]) tg[mt][r] = v;
                    float d = v - mx[mt][r];
                    float e = __expf(-fabsf(d));
                    bool newmax = d > 0.f;
                    ls[mt][r] = fmaf(ls[mt][r], newmax ? e : 1.f, newmax ? 1.f : e);
                    if (newmax) { mx[mt][r] = v; am[mt][r] = n; }
                }
        }

#pragma unroll
        for (int s = 1; s < 16; s <<= 1) {
#pragma unroll
            for (int mt = 0; mt < 2; ++mt)
#pragma unroll
                for (int r = 0; r < 4; ++r) {
                    float mo = __shfl_xor(mx[mt][r], s);
                    float lo = __shfl_xor(ls[mt][r], s);
                    int   ao = __shfl_xor(am[mt][r], s);
                    float to = __shfl_xor(tg[mt][r], s);
                    tg[mt][r] += to;
                    float nm = fmaxf(mx[mt][r], mo);
                    ls[mt][r] = ls[mt][r] * __expf(mx[mt][r] - nm) + lo * __expf(mo - nm);
                    if (mo > mx[mt][r] || (mo == mx[mt][r] && ao < am[mt][r])) am[mt][r] = ao;
                    mx[mt][r] = nm;
                }
        }
        if (ln == 0) {
#pragma unroll
            for (int mt = 0; mt < 2; ++mt)
#pragma unroll
                for (int r = 0; r < 4; ++r) {
                    int row = mt * 16 + lq * 4 + r;
                    S.wred[wave][row][0] = mx[mt][r];
                    S.wred[wave][row][1] = ls[mt][r];
                    S.wred[wave][row][2] = __int_as_float(am[mt][r]);
                    S.wred[wave][row][3] = tg[mt][r];
                }
        }
        __syncthreads();

        float lossv = 0.f, corrv = 0.f;
        if (tid < QG) {
            float m_ = -1e30f, l_ = 0.f, t_ = 0.f; int a_ = 1 << 30;
#pragma unroll
            for (int w = 0; w < 4; ++w) {
                float mo = S.wred[w][tid][0], lo = S.wred[w][tid][1], to = S.wred[w][tid][3];
                int ao = __float_as_int(S.wred[w][tid][2]);
                t_ += to;
                float nm = fmaxf(m_, mo);
                l_ = l_ * __expf(m_ - nm) + lo * __expf(mo - nm);
                if (mo > m_ || (mo == m_ && ao < a_)) a_ = ao;
                m_ = nm;
            }
            lossv = m_ + logf(l_) - t_;
            corrv = (a_ == S.tgts[tid]) ? 1.f : 0.f;
        }
        if (wave == 0) {
            for (int s = 32; s; s >>= 1) {
                lossv += __shfl_down(lossv, s);
                corrv += __shfl_down(corrv, s);
            }
            if (tid == 0) {
                int slot = blockIdx.x & 255;
                atomicAdd(&acc[0 * 256 + slot], lossv);
                atomicAdd(&acc[2 * 256 + slot], corrv);
            }
        }
    } else {
        // ================= P head =================
        PSmem& S = *(PSmem*)smem;
        const int pb = blockIdx.x - 768;
        const int trow = pb >> 4;
        const int b0 = (pb & 15) * PG;
        const int node = (trow == 0) ? 0 : ((trow <= NFWD) ? trow : (TSTEP - trow));

        if (tid < PG) S.widL[tid] = wid[(b0 + tid) * NNODE + node];
        __syncthreads();

        for (int idx = tid; idx < PG * 32; idx += 256) {
            int m = idx >> 5, c = idx & 31;
            *(int4*)&S.XL[m][c * 8] = *(const int4*)&embB[S.widL[m] * HD + c * 8];
        }
        if (trow == 0) {
            int4 z = make_int4(0, 0, 0, 0);
            for (int idx = tid; idx < PG * 32; idx += 256) {
                int m = idx >> 5, c = idx & 31;
                *(int4*)&S.XL[m][256 + c * 8] = z;
            }
        } else {
            const unsigned short* hrow = hsb + (size_t)(trow - 1) * NTREE * HD;
            for (int idx = tid; idx < PG * 32; idx += 256) {
                int m = idx >> 5, c = idx & 31;
                *(int4*)&S.XL[m][256 + c * 8] = *(const int4*)&hrow[(b0 + m) * HD + c * 8];
            }
        }
        for (int idx = tid; idx < PG * 8; idx += 256) {
            int m = idx >> 3, c = idx & 7;
            *(int4*)&S.XL[m][512 + c * 8] = *(const int4*)&tvB[(b0 + m) * LD + c * 8];
        }
        __syncthreads();

        f4v a1[2][4];
#pragma unroll
        for (int mt = 0; mt < 2; ++mt)
#pragma unroll
            for (int nt = 0; nt < 4; ++nt) a1[mt][nt] = (f4v){0.f, 0.f, 0.f, 0.f};
        for (int kt = 0; kt < 18; ++kt) {
            s8v a0 = frag(&S.XL[ln][kt * 32 + lq * 8]);
            s8v am_ = frag(&S.XL[16 + ln][kt * 32 + lq * 8]);
#pragma unroll
            for (int nt = 0; nt < 4; ++nt) {
                int n = wave * 64 + nt * 16 + ln;
                s8v b = frag(&UwT[n * 576 + kt * 32 + lq * 8]);
                a1[0][nt] = __builtin_amdgcn_mfma_f32_16x16x32_bf16(a0, b, a1[0][nt], 0, 0, 0);
                a1[1][nt] = __builtin_amdgcn_mfma_f32_16x16x32_bf16(am_, b, a1[1][nt], 0, 0, 0);
            }
        }
        float part[2][4] = {{0, 0, 0, 0}, {0, 0, 0, 0}};
#pragma unroll
        for (int nt = 0; nt < 4; ++nt) {
            int n = wave * 64 + nt * 16 + ln;
            float ub = Ub[n], us = Usw[n];
#pragma unroll
            for (int mt = 0; mt < 2; ++mt)
#pragma unroll
                for (int r = 0; r < 4; ++r)
                    part[mt][r] += fmaxf(a1[mt][nt][r] + ub, 0.f) * us;
        }
#pragma unroll
        for (int s = 1; s < 16; s <<= 1) {
#pragma unroll
            for (int mt = 0; mt < 2; ++mt)
#pragma unroll
                for (int r = 0; r < 4; ++r)
                    part[mt][r] += __shfl_xor(part[mt][r], s);
        }
        if (ln == 0) {
#pragma unroll
            for (int mt = 0; mt < 2; ++mt)
#pragma unroll
                for (int r = 0; r < 4; ++r)
                    S.wredp[wave][mt * 16 + lq * 4 + r] = part[mt][r];
        }
        __syncthreads();

        float lossv = 0.f, corrv = 0.f;
        if (tid < PG) {
            float p = S.wredp[0][tid] + S.wredp[1][tid] + S.wredp[2][tid] + S.wredp[3][tid] + Usb[0];
            float tgt = (trow < NFWD) ? 1.f : 0.f;
            lossv = fmaxf(p, 0.f) - p * tgt + log1pf(expf(-fabsf(p)));
            corrv = (((p > 0.f) ? 1 : 0) == ((trow < NFWD) ? 1 : 0)) ? 1.f : 0.f;
        }
        if (wave == 0) {
            for (int s = 32; s; s >>= 1) {
                lossv += __shfl_down(lossv, s);
                corrv += __shfl_down(corrv, s);
            }
            if (tid == 0) {
                int slot = blockIdx.x & 255;
                atomicAdd(&acc[1 * 256 + slot], lossv);
                atomicAdd(&acc[3 * 256 + slot], corrv);
            }
        }
    }
}

__global__ void fin_kernel(const float* __restrict__ acc, float* __restrict__ out) {
    const int tid = threadIdx.x;
    const int c = tid >> 6, lane = tid & 63;
    float v = 0.f;
    for (int i = lane; i < 256; i += 64) v += acc[c * 256 + i];
    for (int s = 32; s; s >>= 1) v += __shfl_down(v, s);
    if (lane == 0) {
        const float sc[4] = {1.f / 512.f, 1.f / 512.f, 1.f / 24576.f, 1.f / 48640.f};
        out[c] = v * sc[c];
    }
}

extern "C" void kernel_launch(void* const* d_in, const int* in_sizes, int n_in,
                              void* d_out, int out_size, void* d_ws, size_t ws_size,
                              hipStream_t stream) {
    const int*   wid  = (const int*)  d_in[12];
    const float* tv   = (const float*)d_in[13];
    const float* emb  = (const float*)d_in[14];
    const float* Wz   = (const float*)d_in[15];
    const float* bz   = (const float*)d_in[16];
    const float* Wr   = (const float*)d_in[17];
    const float* Ur   = (const float*)d_in[18];
    const float* br   = (const float*)d_in[19];
    const float* Wh   = (const float*)d_in[20];
    const float* bh   = (const float*)d_in[21];
    const float* Ww   = (const float*)d_in[22];
    const float* Wb   = (const float*)d_in[23];
    const float* Uw   = (const float*)d_in[24];
    const float* Ubias= (const float*)d_in[25];
    const float* Wow  = (const float*)d_in[26];
    const float* Wob  = (const float*)d_in[27];
    const float* Usw  = (const float*)d_in[28];
    const float* Usb  = (const float*)d_in[29];

    char* w = (char*)d_ws;
    float* accb = (float*)w;                                 // 4 KB
    float* xzT  = (float*)(w + 4096);                        // 800*256 f32
    float* xhT  = (float*)(w + 823296);
    float* xrT  = (float*)(w + 1642496);
    unsigned short* WzT2 = (unsigned short*)(w + 2461696);   // [256 n][256 k] bf16
    unsigned short* WhT2 = (unsigned short*)(w + 2592768);
    unsigned short* UrT2 = (unsigned short*)(w + 2723840);
    unsigned short* hsb  = (unsigned short*)(w + 2854912);   // 94*512*256 bf16
    unsigned short* W1T  = (unsigned short*)(w + 27496448);  // [256][320]
    unsigned short* WoT  = (unsigned short*)(w + 27660288);  // [800][256]
    unsigned short* UwT  = (unsigned short*)(w + 28069888);  // [256][576]
    unsigned short* embB = (unsigned short*)(w + 28364800);  // [800][256]
    unsigned short* tvB  = (unsigned short*)(w + 28774400);  // [512][64]

    prep_xproj<<<VOC / PV, 256, 0, stream>>>(emb, Wz, bz, Wh, bh, Wr, br, xzT, xhT, xrT);
    prep_misc<<<3012, 256, 0, stream>>>(Wz, Wh, Ur, Ww, Wow, Uw, emb, tv,
                                        WzT2, WhT2, UrT2, W1T, WoT, UwT,
                                        embB, tvB, accb);
    gru10<<<NTREE / 2, 512, 0, stream>>>(wid, xzT, xhT, xrT, WzT2, WhT2, UrT2, hsb);
    heads<<<768 + 1520, 256, 0, stream>>>(wid, tvB, embB, hsb, W1T, WoT, UwT,
                                          Wb, Wob, Ubias, Usw, Usb, accb);
    fin_kernel<<<1, 256, 0, stream>>>(accb, (float*)d_out);
}